// Round 6
// baseline (176.923 us; speedup 1.0000x reference)
//
#include <hip/hip_runtime.h>
#include <hip/hip_bf16.h>
#include <cstdint>
#include <cstddef>

#define DEVINL __device__ __forceinline__

typedef unsigned short u16;
typedef unsigned int u32;
typedef __attribute__((ext_vector_type(8))) short short8;
typedef __attribute__((ext_vector_type(4))) float f32x4;
typedef __attribute__((ext_vector_type(4))) u16 u16x4;

constexpr int CH = 256;   // channels
constexpr int HW = 4096;  // h*w
constexpr int NB = 4;     // batch
// softmax with fixed max, 2^ domain: P = 2^(S*log2e - M0L) = exp(S - 4.0)
constexpr float M0L = 5.7707801636f;  // 4.0 * log2(e)

DEVINL u16 f2bf(float f) {
  union { float f; u32 u; } v; v.f = f;
  u32 u = v.u;
  u32 r = u + 0x7FFFu + ((u >> 16) & 1u);
  return (u16)(r >> 16);
}
DEVINL float bf2f(u16 h) {
  union { u32 u; float f; } v; v.u = ((u32)h) << 16; return v.f;
}
DEVINL float fexp2(float x) {
  float r; asm("v_exp_f32 %0, %1" : "=v"(r) : "v"(x)); return r;
}
DEVINL u32 cvtpk(float lo, float hi) {
  u32 r; asm("v_cvt_pk_bf16_f32 %0, %1, %2" : "=v"(r) : "v"(lo), "v"(hi)); return r;
}

DEVINL void gl_lds16(const void* g, void* l) {
  __builtin_amdgcn_global_load_lds(
      (__attribute__((address_space(1))) void*)(size_t)g,
      (__attribute__((address_space(3))) void*)l, 16, 0, 0);
}

DEVINL f32x4 mfma_bf16(short8 a, short8 b, f32x4 c) {
  return __builtin_amdgcn_mfma_f32_16x16x32_bf16(a, b, c, 0, 0, 0);
}

// ---------------- K1: groupnorm stats ----------------
__global__ void k_stats(const float* __restrict__ x, float* __restrict__ stats) {
  int bg = blockIdx.x;  // b*32 + g ; each group = contiguous 8*4096 floats
  const float* p = x + (size_t)bg * 32768;
  float s = 0.f, ss = 0.f;
  for (int i = threadIdx.x; i < 8192; i += 256) {
    float4 v = ((const float4*)p)[i];
    s += v.x + v.y + v.z + v.w;
    ss += v.x * v.x + v.y * v.y + v.z * v.z + v.w * v.w;
  }
  for (int m = 32; m; m >>= 1) { s += __shfl_xor(s, m); ss += __shfl_xor(ss, m); }
  __shared__ float rs[4], rss[4];
  int w = threadIdx.x >> 6;
  if ((threadIdx.x & 63) == 0) { rs[w] = s; rss[w] = ss; }
  __syncthreads();
  if (threadIdx.x == 0) {
    s = rs[0] + rs[1] + rs[2] + rs[3];
    ss = rss[0] + rss[1] + rss[2] + rss[3];
    float mean = s / 32768.f;
    float var = ss / 32768.f - mean * mean;
    stats[bg * 2] = mean;
    stats[bg * 2 + 1] = rsqrtf(var + 1e-5f);
  }
}

// ---------------- K2: weights -> bf16 ----------------
__global__ void k_wconv(const float* __restrict__ wq, const float* __restrict__ wo,
                        u16* __restrict__ w3, u16* __restrict__ wob) {
  int i = blockIdx.x * 256 + threadIdx.x;  // grid 768 -> 196608 threads
  w3[i] = f2bf(wq[i]);
  if (i < 65536) wob[i] = f2bf(wo[i]);
}

// ---------------- K3: normalize + transpose to xnT[b][p][c] bf16 ----------------
__global__ void k_norm(const float* __restrict__ x, const float* __restrict__ stats,
                       const float* __restrict__ gamma, const float* __restrict__ beta,
                       u16* __restrict__ xnT) {
  int bid = blockIdx.x;                 // 4 * 4 * 64 = 1024
  int b = bid >> 8, ct = (bid >> 6) & 3, pt = bid & 63;
  int c0 = ct * 64, p0 = pt * 64;
  __shared__ u16 tile[64][66];
  const float* xb = x + ((size_t)b * CH + c0) * HW + p0;
#pragma unroll
  for (int it = 0; it < 4; it++) {
    int li = threadIdx.x + it * 256;
    int ci = li >> 4, pq = (li & 15) * 4;
    float4 v = *(const float4*)(xb + (size_t)ci * HW + pq);
    int c = c0 + ci;
    int gg = c >> 3;
    float mean = stats[(b * 32 + gg) * 2], rstd = stats[(b * 32 + gg) * 2 + 1];
    float ga = gamma[c] * rstd;
    float be = beta[c] - mean * ga;
    tile[ci][pq + 0] = f2bf(v.x * ga + be);
    tile[ci][pq + 1] = f2bf(v.y * ga + be);
    tile[ci][pq + 2] = f2bf(v.z * ga + be);
    tile[ci][pq + 3] = f2bf(v.w * ga + be);
  }
  __syncthreads();
#pragma unroll
  for (int it = 0; it < 2; it++) {
    int ch = threadIdx.x + it * 256;
    int pr = ch >> 3, cc = (ch & 7) * 8;
    short8 res;
#pragma unroll
    for (int q2 = 0; q2 < 8; q2++) res[q2] = (short)tile[cc + q2][pr];
    *(short8*)(xnT + ((size_t)b * HW + p0 + pr) * CH + c0 + cc) = res;
  }
}

// ---------------- shared GEMM staging helper ----------------
DEVINL void stage_tile(char* dst, const u16* src_rows, int kt, int w, int lane) {
#pragma unroll
  for (int it = 0; it < 4; it++) {
    int CI = w * 256 + it * 64 + lane;
    int row = CI >> 3, ci = CI & 7;
    int sci = ci ^ (row & 7);
    gl_lds16(src_rows + (size_t)row * 256 + kt * 64 + sci * 8,
             dst + w * 4096 + it * 1024);
  }
}

DEVINL short8 ldsA(const char* base, int row, int colb) {
  return *(const short8*)(base + row * 128 + (colb ^ ((row & 7) << 4)));
}

// ---------------- K4: QKV GEMM ----------------
__global__ __launch_bounds__(256, 2) void k_qkv(
    const u16* __restrict__ xnT, const u16* __restrict__ w3,
    const float* __restrict__ bqkv,
    u16* __restrict__ Qg, u16* __restrict__ Kg, u16* __restrict__ Vg) {
  int bid = blockIdx.x;  // 4 * 32 * 6
  int b = bid / 192; int rm = bid - b * 192; int mt = rm / 6, nt = rm - mt * 6;
  extern __shared__ char sm[];
  const int tid = threadIdx.x, w = tid >> 6, lane = tid & 63, t = lane & 15, g = lane >> 4;
  const u16* Abase = xnT + ((size_t)b * HW + mt * 128) * CH;
  const u16* Bbase = w3 + (size_t)nt * 128 * CH;
  f32x4 acc[4][4] = {};
  stage_tile(sm, Abase, 0, w, lane);
  stage_tile(sm + 32768, Bbase, 0, w, lane);
  __syncthreads();
  for (int kt = 0; kt < 4; kt++) {
    int cur = kt & 1;
    if (kt < 3) {
      stage_tile(sm + ((cur ^ 1) * 16384), Abase, kt + 1, w, lane);
      stage_tile(sm + 32768 + ((cur ^ 1) * 16384), Bbase, kt + 1, w, lane);
    }
    const char* Asm = sm + cur * 16384;
    const char* Bsm = sm + 32768 + cur * 16384;
#pragma unroll
    for (int ks = 0; ks < 2; ks++) {
      short8 af[4], bf[4];
#pragma unroll
      for (int m = 0; m < 4; m++) af[m] = ldsA(Asm, 64 * (w >> 1) + 16 * m + t, ks * 64 + g * 16);
#pragma unroll
      for (int n = 0; n < 4; n++) bf[n] = ldsA(Bsm, 64 * (w & 1) + 16 * n + t, ks * 64 + g * 16);
#pragma unroll
      for (int m = 0; m < 4; m++)
#pragma unroll
        for (int n = 0; n < 4; n++)
          acc[m][n] = mfma_bf16(af[m], bf[n], acc[m][n]);
    }
    __syncthreads();
  }
  // fold 1/sqrt(256) * log2(e) into Q so attention exp is a raw v_exp_f32
  float scale = (nt < 2) ? 0.0625f * 1.44269504f : 1.0f;
#pragma unroll
  for (int n = 0; n < 4; n++) {
    int o = nt * 128 + 64 * (w & 1) + 16 * n + t;
    float bias = bqkv[o];
#pragma unroll
    for (int m = 0; m < 4; m++) {
      int p0 = mt * 128 + 64 * (w >> 1) + 16 * m + 4 * g;
      if (nt < 4) {
        u16* dst = (nt < 2) ? Qg : Kg;
        int oo = (nt < 2) ? o : o - 256;
#pragma unroll
        for (int rr = 0; rr < 4; rr++) {
          float v = (acc[m][n][rr] + bias) * scale;
          dst[((size_t)b * HW + p0 + rr) * CH + oo] = f2bf(v);
        }
      } else {
        int oo = o - 512;
        u16x4 pv;
#pragma unroll
        for (int rr = 0; rr < 4; rr++) pv[rr] = f2bf(acc[m][n][rr] + bias);
        *(u16x4*)(Vg + (size_t)b * CH * HW + (size_t)oo * HW + p0) = pv;
      }
    }
  }
}

// ---------------- K5: flash attention ----------------
// Qblock 128, KVBLK 32, 8 waves x 16 q-rows, 2 blocks/CU (4 waves/SIMD).
// K: gl_lds dbuf 2x16KB, XOR-swizzled. V: reg-staged into ONE 32KB buffer with
// the double-buffer interleaved into each 128B row (slot ^= cur<<2), XOR-swizzled.
// Swapped QK^T + in-register P via cvt_pk + bpermute. launch_bounds(512,2):
// empirically caps VGPR at 128 (R4); (512,4) forced 64 VGPR -> spills (R5).
__global__ __launch_bounds__(512, 2) void k_attn(
    const u16* __restrict__ Qg, const u16* __restrict__ Kg, const u16* __restrict__ Vg,
    u16* __restrict__ Op, float* __restrict__ ml) {
  int bid = blockIdx.x;  // qb*16 + b*4 + split ; bid%8 -> XCD (KV L2 affinity)
  int qb = bid >> 4, b = (bid >> 2) & 3, split = bid & 3;
  extern __shared__ char sm[];  // K dbuf: 0, 16384 ; V: 32768 (32KB interleaved)
  const int tid = threadIdx.x, w = tid >> 6, lane = tid & 63, t = lane & 15, g = lane >> 4;
  const u16* Qb = Qg + (size_t)b * HW * CH;
  const u16* Kb = Kg + (size_t)b * HW * CH;
  const u16* Vb = Vg + (size_t)b * CH * HW;
  int qrow0 = qb * 128 + w * 16;
  int kv0 = split * 1024;

  short8 qf[8];
#pragma unroll
  for (int ks = 0; ks < 8; ks++)
    qf[ks] = *(const short8*)(Qb + (size_t)(qrow0 + t) * CH + ks * 32 + g * 8);

  f32x4 oacc[16] = {};
  float lsum = 0.f;

  // bpermute source-lane byte addresses
  const int sl0 = (t + ((2 * (g & 1)) << 4)) << 2;
  const int sl1 = (t + ((2 * (g & 1) + 1) << 4)) << 2;
  const bool hiG = g >= 2;

  // staging offsets
  int kOff0, kOff1, vgOff0, vgOff1, vlOff0, vlOff1;
  {
    int CI0 = w * 128 + lane, CI1 = CI0 + 64;
    // K tile [32 kv][256 c]: 1024 chunks of 16B, source-swizzled for linear LDS dest
    int r0 = CI0 >> 5, c0 = CI0 & 31;
    int r1 = CI1 >> 5, c1 = CI1 & 31;
    kOff0 = r0 * CH + ((c0 ^ (r0 & 7)) * 8);
    kOff1 = r1 * CH + ((c1 ^ (r1 & 7)) * 8);
    // V tile [256 ch][2buf x 32 kv] interleaved 128B rows: vc = row, vh = kv-chunk
    int vc0 = CI0 & 255, vh0 = CI0 >> 8;
    int vc1 = CI1 & 255, vh1 = CI1 >> 8;
    vgOff0 = vc0 * HW + vh0 * 8;
    vgOff1 = vc1 * HW + vh1 * 8;
    vlOff0 = vc0 * 128 + (((vh0 ^ (vc0 & 7)) & 7) << 4);
    vlOff1 = vc1 * 128 + (((vh1 ^ (vc1 & 7)) & 7) << 4);
  }
  const int vrOff = t * 128 + ((g ^ (t & 7)) << 4);  // read: ^ (cur<<6), + cf*2048
  char* VB = sm + 32768;

  // prologue: issue V(0) reg loads, then K(0) gl_lds (order matters for vmcnt)
  const u16* vs0 = Vb + kv0;
  const u16* ks0 = Kb + (size_t)kv0 * CH;
  short8 vA = *(const short8*)(vs0 + vgOff0);
  short8 vB = *(const short8*)(vs0 + vgOff1);
  __builtin_amdgcn_sched_barrier(0);
  gl_lds16(ks0 + kOff0, sm + w * 2048);
  gl_lds16(ks0 + kOff1, sm + w * 2048 + 1024);

  for (int tt = 0; tt < 32; tt++) {
    int cur = tt & 1, nxt = cur ^ 1;
    // write V(cur) regs to LDS (compiler inserts the wait for vA/vB)
    *(short8*)(VB + (vlOff0 ^ (cur << 6))) = vA;
    *(short8*)(VB + (vlOff1 ^ (cur << 6))) = vB;
    // issue next tile's loads (wrap keeps counts uniform)
    int tn = (tt + 1) & 31;
    const u16* vsn = Vb + kv0 + tn * 32;
    const u16* ksn = Kb + (size_t)(kv0 + tn * 32) * CH;
    vA = *(const short8*)(vsn + vgOff0);
    vB = *(const short8*)(vsn + vgOff1);
    __builtin_amdgcn_sched_barrier(0);
    char* KLn = sm + (nxt << 14) + w * 2048;
    gl_lds16(ksn + kOff0, KLn);
    gl_lds16(ksn + kOff1, KLn + 1024);
    asm volatile("s_waitcnt vmcnt(4)" ::: "memory");   // K(cur) landed; 4 newest in flight
    asm volatile("s_waitcnt lgkmcnt(0)" ::: "memory"); // ds_writes visible
    __builtin_amdgcn_s_barrier();
    __builtin_amdgcn_sched_barrier(0);
    const char* KL = sm + (cur << 14);
    // S^T = K . Q^T : lane(t,g) holds P[q=t][kv = 16jf + 4g + rr]
    f32x4 s0 = {}, s1 = {};
    __builtin_amdgcn_s_setprio(1);
#pragma unroll
    for (int ks = 0; ks < 8; ks++) {
      int cb = (ks * 64 + g * 16) ^ ((t & 7) << 4);
      short8 kf0 = *(const short8*)(KL + t * 512 + cb);
      short8 kf1 = *(const short8*)(KL + (16 + t) * 512 + cb);
      s0 = mfma_bf16(kf0, qf[ks], s0);
      s1 = mfma_bf16(kf1, qf[ks], s1);
    }
    __builtin_amdgcn_s_setprio(0);
    // P = exp2(S' - M0L); pack bf16 pairs; accumulate row-sum partials
    float e0 = fexp2(s0[0] - M0L), e1 = fexp2(s0[1] - M0L);
    float e2 = fexp2(s0[2] - M0L), e3 = fexp2(s0[3] - M0L);
    float f0 = fexp2(s1[0] - M0L), f1 = fexp2(s1[1] - M0L);
    float f2 = fexp2(s1[2] - M0L), f3 = fexp2(s1[3] - M0L);
    lsum += (e0 + e1) + (e2 + e3) + (f0 + f1) + (f2 + f3);
    u32 A00 = cvtpk(e0, e1), A01 = cvtpk(e2, e3);
    u32 A10 = cvtpk(f0, f1), A11 = cvtpk(f2, f3);
    // redistribute D-frag -> A-frag: lane(t,g) word w takes A[g>>1][w&1] from
    // lane t + 16*(2(g&1) + (w>>1))
    u32 w0a = (u32)__builtin_amdgcn_ds_bpermute(sl0, (int)A00);
    u32 w0b = (u32)__builtin_amdgcn_ds_bpermute(sl0, (int)A10);
    u32 w1a = (u32)__builtin_amdgcn_ds_bpermute(sl0, (int)A01);
    u32 w1b = (u32)__builtin_amdgcn_ds_bpermute(sl0, (int)A11);
    u32 w2a = (u32)__builtin_amdgcn_ds_bpermute(sl1, (int)A00);
    u32 w2b = (u32)__builtin_amdgcn_ds_bpermute(sl1, (int)A10);
    u32 w3a = (u32)__builtin_amdgcn_ds_bpermute(sl1, (int)A01);
    u32 w3b = (u32)__builtin_amdgcn_ds_bpermute(sl1, (int)A11);
    union { u32 u[4]; short8 s8; } pk;
    pk.u[0] = hiG ? w0b : w0a;
    pk.u[1] = hiG ? w1b : w1a;
    pk.u[2] = hiG ? w2b : w2a;
    pk.u[3] = hiG ? w3b : w3a;
    short8 pf = pk.s8;
    // PV
    __builtin_amdgcn_s_setprio(1);
#pragma unroll
    for (int cf = 0; cf < 16; cf++) {
      short8 vf = *(const short8*)(VB + cf * 2048 + (vrOff ^ (cur << 6)));
      oacc[cf] = mfma_bf16(pf, vf, oacc[cf]);
    }
    __builtin_amdgcn_s_setprio(0);
    __builtin_amdgcn_s_barrier();  // all done reading buf[cur]
  }
  // store unnormalized partial O (bf16) + l
  size_t obase = (size_t)(split * NB + b) * HW;
#pragma unroll
  for (int cf = 0; cf < 16; cf++)
#pragma unroll
    for (int rr = 0; rr < 4; rr++) {
      int row = qrow0 + 4 * g + rr;
      Op[(obase + row) * CH + cf * 16 + t] = f2bf(oacc[cf][rr]);
    }
  // full row-sum: reduce partials across the 4 g-groups (lanes t+16g hold q=t)
  lsum += __shfl_xor(lsum, 16);
  lsum += __shfl_xor(lsum, 32);
  if (g == 0) ml[obase + qrow0 + t] = lsum;
}

// ---------------- K6: merge 4 KV splits ----------------
__global__ void k_merge(const u16* __restrict__ Op, const float* __restrict__ ml,
                        u16* __restrict__ AO) {
  int idx = blockIdx.x * 256 + threadIdx.x;  // 4*4096*32
  int c8 = idx & 31, row = (idx >> 5) & 4095, b = idx >> 17;
  float acc[8] = {};
  float l = 0.f;
#pragma unroll
  for (int s = 0; s < 4; s++) {
    size_t r = (size_t)(s * NB + b) * HW + row;
    l += ml[r];
    short8 a = *(const short8*)(Op + r * CH + c8 * 8);
#pragma unroll
    for (int q2 = 0; q2 < 8; q2++) acc[q2] += bf2f((u16)a[q2]);
  }
  float inv = 1.f / l;
  short8 res;
#pragma unroll
  for (int q2 = 0; q2 < 8; q2++) res[q2] = (short)f2bf(acc[q2] * inv);
  *(short8*)(AO + ((size_t)b * HW + row) * CH + c8 * 8) = res;
}

// ---------------- K7: output projection + residual ----------------
__global__ __launch_bounds__(256, 2) void k_oproj(
    const u16* __restrict__ wob, const u16* __restrict__ AO,
    const float* __restrict__ bout, const float* __restrict__ x,
    float* __restrict__ out) {
  int bid = blockIdx.x;  // b*64 + mt*32 + nt
  int b = bid >> 6, mt = (bid >> 5) & 1, nt = bid & 31;
  extern __shared__ char sm[];
  const int tid = threadIdx.x, w = tid >> 6, lane = tid & 63, t = lane & 15, g = lane >> 4;
  const u16* Abase = wob + (size_t)mt * 128 * CH;
  const u16* Bbase = AO + ((size_t)b * HW + nt * 128) * CH;
  f32x4 acc[4][4] = {};
  stage_tile(sm, Abase, 0, w, lane);
  stage_tile(sm + 32768, Bbase, 0, w, lane);
  __syncthreads();
  for (int kt = 0; kt < 4; kt++) {
    int cur = kt & 1;
    if (kt < 3) {
      stage_tile(sm + ((cur ^ 1) * 16384), Abase, kt + 1, w, lane);
      stage_tile(sm + 32768 + ((cur ^ 1) * 16384), Bbase, kt + 1, w, lane);
    }
    const char* Asm = sm + cur * 16384;
    const char* Bsm = sm + 32768 + cur * 16384;
#pragma unroll
    for (int ks = 0; ks < 2; ks++) {
      short8 af[4], bf[4];
#pragma unroll
      for (int m = 0; m < 4; m++) af[m] = ldsA(Asm, 64 * (w >> 1) + 16 * m + t, ks * 64 + g * 16);
#pragma unroll
      for (int n = 0; n < 4; n++) bf[n] = ldsA(Bsm, 64 * (w & 1) + 16 * n + t, ks * 64 + g * 16);
#pragma unroll
      for (int m = 0; m < 4; m++)
#pragma unroll
        for (int n = 0; n < 4; n++)
          acc[m][n] = mfma_bf16(af[m], bf[n], acc[m][n]);
    }
    __syncthreads();
  }
#pragma unroll
  for (int m = 0; m < 4; m++) {
    int o0 = mt * 128 + 64 * (w >> 1) + 16 * m + 4 * g;
#pragma unroll
    for (int n = 0; n < 4; n++) {
      int p = nt * 128 + 64 * (w & 1) + 16 * n + t;
#pragma unroll
      for (int rr = 0; rr < 4; rr++) {
        int o = o0 + rr;
        size_t off = ((size_t)b * CH + o) * HW + p;
        out[off] = acc[m][n][rr] + bout[o] + x[off];
      }
    }
  }
}

extern "C" void kernel_launch(void* const* d_in, const int* in_sizes, int n_in,
                              void* d_out, int out_size, void* d_ws, size_t ws_size,
                              hipStream_t stream) {
  const float* x = (const float*)d_in[0];
  const float* gamma = (const float*)d_in[1];
  const float* beta = (const float*)d_in[2];
  const float* wqkv = (const float*)d_in[3];
  const float* bqkv = (const float*)d_in[4];
  const float* wout = (const float*)d_in[5];
  const float* bout = (const float*)d_in[6];
  float* out = (float*)d_out;
  char* ws = (char*)d_ws;

  float* stats = (float*)(ws);                                  // 1 KB
  u16* w3 = (u16*)(ws + 1024);                                  // 384 KB
  u16* wob = (u16*)(ws + 1024 + 393216);                        // 128 KB
  u16* xnT = (u16*)(ws + 525312);                               // 8 MB
  u16* Qg = (u16*)(ws + 525312 + 1ull * 8388608);               // 8 MB
  u16* Kg = (u16*)(ws + 525312 + 2ull * 8388608);               // 8 MB
  u16* Vg = (u16*)(ws + 525312 + 3ull * 8388608);               // 8 MB
  u16* Op = (u16*)(ws + 525312 + 4ull * 8388608);               // 32 MB (4 splits)
  float* ml = (float*)(ws + 525312 + 8ull * 8388608);           // 256 KB
  u16* AO = xnT;  // alias: xnT dead after k_qkv

  hipFuncSetAttribute(reinterpret_cast<const void*>(k_qkv),
                      hipFuncAttributeMaxDynamicSharedMemorySize, 65536);
  hipFuncSetAttribute(reinterpret_cast<const void*>(k_oproj),
                      hipFuncAttributeMaxDynamicSharedMemorySize, 65536);
  hipFuncSetAttribute(reinterpret_cast<const void*>(k_attn),
                      hipFuncAttributeMaxDynamicSharedMemorySize, 65536);

  k_stats<<<128, 256, 0, stream>>>(x, stats);
  k_wconv<<<768, 256, 0, stream>>>(wqkv, wout, w3, wob);
  k_norm<<<1024, 256, 0, stream>>>(x, stats, gamma, beta, xnT);
  k_qkv<<<768, 256, 65536, stream>>>(xnT, w3, bqkv, Qg, Kg, Vg);
  k_attn<<<512, 512, 65536, stream>>>(Qg, Kg, Vg, Op, ml);
  k_merge<<<2048, 256, 0, stream>>>(Op, ml, AO);
  k_oproj<<<256, 256, 65536, stream>>>(wob, AO, bout, x, out);
}

// Round 7
// 150.585 us; speedup vs baseline: 1.1749x; 1.1749x over previous
//
#include <hip/hip_runtime.h>
#include <hip/hip_bf16.h>
#include <cstdint>
#include <cstddef>

#define DEVINL __device__ __forceinline__

typedef unsigned short u16;
typedef unsigned int u32;
typedef __attribute__((ext_vector_type(8))) short short8;
typedef __attribute__((ext_vector_type(4))) float f32x4;
typedef __attribute__((ext_vector_type(4))) u16 u16x4;

constexpr int CH = 256;   // channels
constexpr int HW = 4096;  // h*w
constexpr int NB = 4;     // batch
// softmax with fixed max, 2^ domain: P = 2^(S*log2e - M0L) = exp(S - 4.0)
constexpr float M0L = 5.7707801636f;  // 4.0 * log2(e)

DEVINL u16 f2bf(float f) {
  union { float f; u32 u; } v; v.f = f;
  u32 u = v.u;
  u32 r = u + 0x7FFFu + ((u >> 16) & 1u);
  return (u16)(r >> 16);
}
DEVINL float bf2f(u16 h) {
  union { u32 u; float f; } v; v.u = ((u32)h) << 16; return v.f;
}
DEVINL float fexp2(float x) {
  float r; asm("v_exp_f32 %0, %1" : "=v"(r) : "v"(x)); return r;
}
DEVINL u32 cvtpk(float lo, float hi) {
  u32 r; asm("v_cvt_pk_bf16_f32 %0, %1, %2" : "=v"(r) : "v"(lo), "v"(hi)); return r;
}

DEVINL void gl_lds16(const void* g, void* l) {
  __builtin_amdgcn_global_load_lds(
      (__attribute__((address_space(1))) void*)(size_t)g,
      (__attribute__((address_space(3))) void*)l, 16, 0, 0);
}

DEVINL f32x4 mfma_bf16(short8 a, short8 b, f32x4 c) {
  return __builtin_amdgcn_mfma_f32_16x16x32_bf16(a, b, c, 0, 0, 0);
}

// ---------------- K1: groupnorm stats + weight cast (fused) ----------------
__global__ void k_pre(const float* __restrict__ x, float* __restrict__ stats,
                      const float* __restrict__ wq, const float* __restrict__ wo,
                      u16* __restrict__ w3, u16* __restrict__ wob) {
  if (blockIdx.x >= 128) {
    int i = (blockIdx.x - 128) * 256 + threadIdx.x;  // 768 blocks -> 196608
    w3[i] = f2bf(wq[i]);
    if (i < 65536) wob[i] = f2bf(wo[i]);
    return;
  }
  int bg = blockIdx.x;  // b*32 + g ; each group = contiguous 8*4096 floats
  const float* p = x + (size_t)bg * 32768;
  float s = 0.f, ss = 0.f;
  for (int i = threadIdx.x; i < 8192; i += 256) {
    float4 v = ((const float4*)p)[i];
    s += v.x + v.y + v.z + v.w;
    ss += v.x * v.x + v.y * v.y + v.z * v.z + v.w * v.w;
  }
  for (int m = 32; m; m >>= 1) { s += __shfl_xor(s, m); ss += __shfl_xor(ss, m); }
  __shared__ float rs[4], rss[4];
  int w = threadIdx.x >> 6;
  if ((threadIdx.x & 63) == 0) { rs[w] = s; rss[w] = ss; }
  __syncthreads();
  if (threadIdx.x == 0) {
    s = rs[0] + rs[1] + rs[2] + rs[3];
    ss = rss[0] + rss[1] + rss[2] + rss[3];
    float mean = s / 32768.f;
    float var = ss / 32768.f - mean * mean;
    stats[bg * 2] = mean;
    stats[bg * 2 + 1] = rsqrtf(var + 1e-5f);
  }
}

// ---------------- K3: normalize + transpose to xnT[b][p][c] bf16 ----------------
__global__ void k_norm(const float* __restrict__ x, const float* __restrict__ stats,
                       const float* __restrict__ gamma, const float* __restrict__ beta,
                       u16* __restrict__ xnT) {
  int bid = blockIdx.x;                 // 4 * 4 * 64 = 1024
  int b = bid >> 8, ct = (bid >> 6) & 3, pt = bid & 63;
  int c0 = ct * 64, p0 = pt * 64;
  __shared__ u16 tile[64][66];
  const float* xb = x + ((size_t)b * CH + c0) * HW + p0;
#pragma unroll
  for (int it = 0; it < 4; it++) {
    int li = threadIdx.x + it * 256;
    int ci = li >> 4, pq = (li & 15) * 4;
    float4 v = *(const float4*)(xb + (size_t)ci * HW + pq);
    int c = c0 + ci;
    int gg = c >> 3;
    float mean = stats[(b * 32 + gg) * 2], rstd = stats[(b * 32 + gg) * 2 + 1];
    float ga = gamma[c] * rstd;
    float be = beta[c] - mean * ga;
    tile[ci][pq + 0] = f2bf(v.x * ga + be);
    tile[ci][pq + 1] = f2bf(v.y * ga + be);
    tile[ci][pq + 2] = f2bf(v.z * ga + be);
    tile[ci][pq + 3] = f2bf(v.w * ga + be);
  }
  __syncthreads();
#pragma unroll
  for (int it = 0; it < 2; it++) {
    int ch = threadIdx.x + it * 256;
    int pr = ch >> 3, cc = (ch & 7) * 8;
    short8 res;
#pragma unroll
    for (int q2 = 0; q2 < 8; q2++) res[q2] = (short)tile[cc + q2][pr];
    *(short8*)(xnT + ((size_t)b * HW + p0 + pr) * CH + c0 + cc) = res;
  }
}

// ---------------- shared GEMM staging helper ----------------
DEVINL void stage_tile(char* dst, const u16* src_rows, int kt, int w, int lane) {
#pragma unroll
  for (int it = 0; it < 4; it++) {
    int CI = w * 256 + it * 64 + lane;
    int row = CI >> 3, ci = CI & 7;
    int sci = ci ^ (row & 7);
    gl_lds16(src_rows + (size_t)row * 256 + kt * 64 + sci * 8,
             dst + w * 4096 + it * 1024);
  }
}

DEVINL short8 ldsA(const char* base, int row, int colb) {
  return *(const short8*)(base + row * 128 + (colb ^ ((row & 7) << 4)));
}

// ---------------- K4: QKV GEMM ----------------
__global__ __launch_bounds__(256, 2) void k_qkv(
    const u16* __restrict__ xnT, const u16* __restrict__ w3,
    const float* __restrict__ bqkv,
    u16* __restrict__ Qg, u16* __restrict__ Kg, u16* __restrict__ Vg) {
  int bid = blockIdx.x;  // 4 * 32 * 6
  int b = bid / 192; int rm = bid - b * 192; int mt = rm / 6, nt = rm - mt * 6;
  extern __shared__ char sm[];
  const int tid = threadIdx.x, w = tid >> 6, lane = tid & 63, t = lane & 15, g = lane >> 4;
  const u16* Abase = xnT + ((size_t)b * HW + mt * 128) * CH;
  const u16* Bbase = w3 + (size_t)nt * 128 * CH;
  f32x4 acc[4][4] = {};
  stage_tile(sm, Abase, 0, w, lane);
  stage_tile(sm + 32768, Bbase, 0, w, lane);
  __syncthreads();
  for (int kt = 0; kt < 4; kt++) {
    int cur = kt & 1;
    if (kt < 3) {
      stage_tile(sm + ((cur ^ 1) * 16384), Abase, kt + 1, w, lane);
      stage_tile(sm + 32768 + ((cur ^ 1) * 16384), Bbase, kt + 1, w, lane);
    }
    const char* Asm = sm + cur * 16384;
    const char* Bsm = sm + 32768 + cur * 16384;
#pragma unroll
    for (int ks = 0; ks < 2; ks++) {
      short8 af[4], bf[4];
#pragma unroll
      for (int m = 0; m < 4; m++) af[m] = ldsA(Asm, 64 * (w >> 1) + 16 * m + t, ks * 64 + g * 16);
#pragma unroll
      for (int n = 0; n < 4; n++) bf[n] = ldsA(Bsm, 64 * (w & 1) + 16 * n + t, ks * 64 + g * 16);
#pragma unroll
      for (int m = 0; m < 4; m++)
#pragma unroll
        for (int n = 0; n < 4; n++)
          acc[m][n] = mfma_bf16(af[m], bf[n], acc[m][n]);
    }
    __syncthreads();
  }
  // fold 1/sqrt(256) * log2(e) into Q so attention exp is a raw v_exp_f32
  float scale = (nt < 2) ? 0.0625f * 1.44269504f : 1.0f;
#pragma unroll
  for (int n = 0; n < 4; n++) {
    int o = nt * 128 + 64 * (w & 1) + 16 * n + t;
    float bias = bqkv[o];
#pragma unroll
    for (int m = 0; m < 4; m++) {
      int p0 = mt * 128 + 64 * (w >> 1) + 16 * m + 4 * g;
      if (nt < 4) {
        u16* dst = (nt < 2) ? Qg : Kg;
        int oo = (nt < 2) ? o : o - 256;
#pragma unroll
        for (int rr = 0; rr < 4; rr++) {
          float v = (acc[m][n][rr] + bias) * scale;
          dst[((size_t)b * HW + p0 + rr) * CH + oo] = f2bf(v);
        }
      } else {
        int oo = o - 512;
        u16x4 pv;
#pragma unroll
        for (int rr = 0; rr < 4; rr++) pv[rr] = f2bf(acc[m][n][rr] + bias);
        *(u16x4*)(Vg + (size_t)b * CH * HW + (size_t)oo * HW + p0) = pv;
      }
    }
  }
}

// ---------------- K5: flash attention (R4 shape + P-lag-1 schedule) ----------------
// Qblock 256, KVBLK 64, 8 waves, KV-split 4. Per iter:
//   [vmcnt(0)+barrier] PV(t-1) ; QK(t) ; [barrier] stage(t+1) ; SM(t)
// SM overlaps the staging DMA instead of sitting between the MFMA clusters.
__global__ __launch_bounds__(512, 2) void k_attn(
    const u16* __restrict__ Qg, const u16* __restrict__ Kg, const u16* __restrict__ Vg,
    u16* __restrict__ Op, float* __restrict__ ml) {
  int bid = blockIdx.x;  // qb*16 + b*4 + split  (bid%8 -> XCD KV L2 affinity)
  int qb = bid >> 4, b = (bid >> 2) & 3, split = bid & 3;
  extern __shared__ char sm[];  // K dbuf 2x32KB @0, V dbuf 2x32KB @65536
  const int tid = threadIdx.x, w = tid >> 6, lane = tid & 63, t = lane & 15, g = lane >> 4;
  const u16* Qb = Qg + (size_t)b * HW * CH;
  const u16* Kb = Kg + (size_t)b * HW * CH;
  const u16* Vb = Vg + (size_t)b * CH * HW;
  int qrow0 = qb * 256 + w * 32;
  int kv0 = split * 1024;

  short8 q[2][8];
#pragma unroll
  for (int rf = 0; rf < 2; rf++)
#pragma unroll
    for (int ks = 0; ks < 8; ks++)
      q[rf][ks] = *(const short8*)(Qb + (size_t)(qrow0 + rf * 16 + t) * CH + ks * 32 + g * 8);

  f32x4 oacc[2][16] = {};
  float lsum[2] = {0.f, 0.f};
  f32x4 sf[2][4];      // S^T of tile t (QK -> SM)
  short8 pf[2][2];     // P A-frags of tile t (SM -> next iter's PV)

  // bpermute source-lane byte addresses
  const int sl0 = (t + (((2 * g) & 3) << 4)) << 2;
  const int sl1 = (t + (((2 * g + 1) & 3) << 4)) << 2;
  const bool hiG = g >= 2;

  // precomputed per-lane staging offsets (elements)
  size_t kOffE[4], vOffE[4];
#pragma unroll
  for (int it = 0; it < 4; it++) {
    int CI = w * 256 + it * 64 + lane;
    int row = CI >> 5, ci = CI & 31;
    kOffE[it] = (size_t)row * CH + ((ci ^ (row & 7)) * 8);
    int rowv = CI >> 3, civ = CI & 7;
    vOffE[it] = (size_t)rowv * HW + ((civ ^ (rowv & 7)) * 8);
  }
  auto stageKV = [&](int buf, int tt) {
    char* KL = sm + (buf << 15) + w * 4096;
    char* VL = sm + 65536 + (buf << 15) + w * 4096;
    const u16* ksrc = Kb + (size_t)(kv0 + tt * 64) * CH;
    const u16* vsrc = Vb + (kv0 + tt * 64);
#pragma unroll
    for (int it = 0; it < 4; it++) gl_lds16(ksrc + kOffE[it], KL + it * 1024);
#pragma unroll
    for (int it = 0; it < 4; it++) gl_lds16(vsrc + vOffE[it], VL + it * 1024);
  };

  auto QK = [&](const char* KL) {
    __builtin_amdgcn_s_setprio(1);
#pragma unroll
    for (int jf = 0; jf < 4; jf++) {
      f32x4 a0 = {}, a1 = {};
#pragma unroll
      for (int ks = 0; ks < 8; ks++) {
        int row = jf * 16 + t;
        short8 kf = *(const short8*)(KL + row * 512 + ((ks * 64 + g * 16) ^ ((row & 7) << 4)));
        a0 = mfma_bf16(kf, q[0][ks], a0);
        a1 = mfma_bf16(kf, q[1][ks], a1);
      }
      sf[0][jf] = a0; sf[1][jf] = a1;
    }
    __builtin_amdgcn_s_setprio(0);
  };
  auto PV = [&](const char* VL) {
    __builtin_amdgcn_s_setprio(1);
#pragma unroll
    for (int ks = 0; ks < 2; ks++)
#pragma unroll
      for (int cf = 0; cf < 16; cf++) {
        int row = cf * 16 + t;
        short8 vf = *(const short8*)(VL + row * 128 + ((ks * 64 + g * 16) ^ ((row & 7) << 4)));
        oacc[0][cf] = mfma_bf16(pf[0][ks], vf, oacc[0][cf]);
        oacc[1][cf] = mfma_bf16(pf[1][ks], vf, oacc[1][cf]);
      }
    __builtin_amdgcn_s_setprio(0);
  };
  auto SM = [&]() {
#pragma unroll
    for (int rf = 0; rf < 2; rf++) {
      u32 A[4][2];
#pragma unroll
      for (int jf = 0; jf < 4; jf++) {
        float e0 = fexp2(sf[rf][jf][0] - M0L);
        float e1 = fexp2(sf[rf][jf][1] - M0L);
        float e2 = fexp2(sf[rf][jf][2] - M0L);
        float e3 = fexp2(sf[rf][jf][3] - M0L);
        lsum[rf] += (e0 + e1) + (e2 + e3);
        A[jf][0] = cvtpk(e0, e1);
        A[jf][1] = cvtpk(e2, e3);
      }
#pragma unroll
      for (int ks = 0; ks < 2; ks++) {
        int jA = 2 * ks, jB = 2 * ks + 1;
        u32 w0a = (u32)__builtin_amdgcn_ds_bpermute(sl0, (int)A[jA][0]);
        u32 w0b = (u32)__builtin_amdgcn_ds_bpermute(sl0, (int)A[jB][0]);
        u32 w1a = (u32)__builtin_amdgcn_ds_bpermute(sl0, (int)A[jA][1]);
        u32 w1b = (u32)__builtin_amdgcn_ds_bpermute(sl0, (int)A[jB][1]);
        u32 w2a = (u32)__builtin_amdgcn_ds_bpermute(sl1, (int)A[jA][0]);
        u32 w2b = (u32)__builtin_amdgcn_ds_bpermute(sl1, (int)A[jB][0]);
        u32 w3a = (u32)__builtin_amdgcn_ds_bpermute(sl1, (int)A[jA][1]);
        u32 w3b = (u32)__builtin_amdgcn_ds_bpermute(sl1, (int)A[jB][1]);
        union { u32 u[4]; short8 s8; } pk;
        pk.u[0] = hiG ? w0b : w0a;
        pk.u[1] = hiG ? w1b : w1a;
        pk.u[2] = hiG ? w2b : w2a;
        pk.u[3] = hiG ? w3b : w3a;
        pf[rf][ks] = pk.s8;
      }
    }
  };

  // prologue: stage tile 0, compute P(0)
  stageKV(0, 0);
  asm volatile("s_waitcnt vmcnt(0)" ::: "memory");
  __builtin_amdgcn_s_barrier();
  __builtin_amdgcn_sched_barrier(0);
  QK(sm + 0);
  stageKV(1, 1);
  SM();

  for (int tt = 1; tt < 16; tt++) {
    int cur = tt & 1, prv = cur ^ 1;
    asm volatile("s_waitcnt vmcnt(0)" ::: "memory");  // stage(tt) landed
    __builtin_amdgcn_s_barrier();
    __builtin_amdgcn_sched_barrier(0);
    PV(sm + 65536 + (prv << 15));   // P(tt-1) x V(tt-1)
    QK(sm + (cur << 15));           // S(tt)
    __builtin_amdgcn_s_barrier();   // everyone done reading buf prv
    __builtin_amdgcn_sched_barrier(0);
    stageKV(prv, (tt + 1) & 15);    // overwrite prv with tile tt+1
    SM();                           // P(tt), overlaps staging DMA
  }
  PV(sm + 65536 + (1 << 15));       // P(15) x V(15) (buf1; stage(16) wrote buf0)

  // store unnormalized partial O (bf16) + row-sums
  size_t obase = (size_t)(split * NB + b) * HW;
#pragma unroll
  for (int rf = 0; rf < 2; rf++) {
#pragma unroll
    for (int cf = 0; cf < 16; cf++)
#pragma unroll
      for (int rr = 0; rr < 4; rr++) {
        int row = qrow0 + rf * 16 + 4 * g + rr;
        Op[(obase + row) * CH + cf * 16 + t] = f2bf(oacc[rf][cf][rr]);
      }
    float ls = lsum[rf];
    ls += __shfl_xor(ls, 16);
    ls += __shfl_xor(ls, 32);
    if (g == 0) ml[obase + qrow0 + rf * 16 + t] = ls;
  }
}

// ---------------- K7: output projection + residual (merge fused) ----------------
// B tile staged by merging the 4 KV-split partials in registers -> ds_write.
__global__ __launch_bounds__(256, 2) void k_oproj(
    const u16* __restrict__ wob, const u16* __restrict__ Op, const float* __restrict__ ml,
    const float* __restrict__ bout, const float* __restrict__ x,
    float* __restrict__ out) {
  int bid = blockIdx.x;  // b*64 + mt*32 + nt
  int b = bid >> 6, mt = (bid >> 5) & 1, nt = bid & 31;
  extern __shared__ char sm[];
  const int tid = threadIdx.x, w = tid >> 6, lane = tid & 63, t = lane & 15, g = lane >> 4;
  const u16* Abase = wob + (size_t)mt * 128 * CH;

  auto stageB = [&](char* dst, int kt) {
#pragma unroll
    for (int it = 0; it < 4; it++) {
      int CI = w * 256 + it * 64 + lane;
      int row = CI >> 3, ci = CI & 7;
      int sci = ci ^ (row & 7);
      int p = nt * 128 + row;
      float l = 0.f;
      float accv[8] = {};
#pragma unroll
      for (int s = 0; s < 4; s++) {
        size_t r = (size_t)(s * NB + b) * HW + p;
        l += ml[r];
        short8 a = *(const short8*)(Op + r * CH + kt * 64 + sci * 8);
#pragma unroll
        for (int q2 = 0; q2 < 8; q2++) accv[q2] += bf2f((u16)a[q2]);
      }
      float inv = 1.f / l;
      short8 res;
#pragma unroll
      for (int q2 = 0; q2 < 8; q2++) res[q2] = (short)f2bf(accv[q2] * inv);
      *(short8*)(dst + CI * 16) = res;
    }
  };

  f32x4 acc[4][4] = {};
  stage_tile(sm, Abase, 0, w, lane);
  stageB(sm + 32768, 0);
  __syncthreads();
  for (int kt = 0; kt < 4; kt++) {
    int cur = kt & 1;
    if (kt < 3) {
      stage_tile(sm + ((cur ^ 1) * 16384), Abase, kt + 1, w, lane);
      stageB(sm + 32768 + ((cur ^ 1) * 16384), kt + 1);
    }
    const char* Asm = sm + cur * 16384;
    const char* Bsm = sm + 32768 + cur * 16384;
#pragma unroll
    for (int ks = 0; ks < 2; ks++) {
      short8 af[4], bf[4];
#pragma unroll
      for (int m = 0; m < 4; m++) af[m] = ldsA(Asm, 64 * (w >> 1) + 16 * m + t, ks * 64 + g * 16);
#pragma unroll
      for (int n = 0; n < 4; n++) bf[n] = ldsA(Bsm, 64 * (w & 1) + 16 * n + t, ks * 64 + g * 16);
#pragma unroll
      for (int m = 0; m < 4; m++)
#pragma unroll
        for (int n = 0; n < 4; n++)
          acc[m][n] = mfma_bf16(af[m], bf[n], acc[m][n]);
    }
    __syncthreads();
  }
#pragma unroll
  for (int m = 0; m < 4; m++) {
    int o0 = mt * 128 + 64 * (w >> 1) + 16 * m + 4 * g;
#pragma unroll
    for (int n = 0; n < 4; n++) {
      int p = nt * 128 + 64 * (w & 1) + 16 * n + t;
#pragma unroll
      for (int rr = 0; rr < 4; rr++) {
        int o = o0 + rr;
        size_t off = ((size_t)b * CH + o) * HW + p;
        out[off] = acc[m][n][rr] + bout[o] + x[off];
      }
    }
  }
}

extern "C" void kernel_launch(void* const* d_in, const int* in_sizes, int n_in,
                              void* d_out, int out_size, void* d_ws, size_t ws_size,
                              hipStream_t stream) {
  const float* x = (const float*)d_in[0];
  const float* gamma = (const float*)d_in[1];
  const float* beta = (const float*)d_in[2];
  const float* wqkv = (const float*)d_in[3];
  const float* bqkv = (const float*)d_in[4];
  const float* wout = (const float*)d_in[5];
  const float* bout = (const float*)d_in[6];
  float* out = (float*)d_out;
  char* ws = (char*)d_ws;

  float* stats = (float*)(ws);                                  // 1 KB
  u16* w3 = (u16*)(ws + 1024);                                  // 384 KB
  u16* wob = (u16*)(ws + 1024 + 393216);                        // 128 KB
  u16* xnT = (u16*)(ws + 525312);                               // 8 MB
  u16* Qg = (u16*)(ws + 525312 + 1ull * 8388608);               // 8 MB
  u16* Kg = (u16*)(ws + 525312 + 2ull * 8388608);               // 8 MB
  u16* Vg = (u16*)(ws + 525312 + 3ull * 8388608);               // 8 MB
  u16* Op = (u16*)(ws + 525312 + 4ull * 8388608);               // 32 MB (4 splits)
  float* ml = (float*)(ws + 525312 + 8ull * 8388608);           // 256 KB

  hipFuncSetAttribute(reinterpret_cast<const void*>(k_qkv),
                      hipFuncAttributeMaxDynamicSharedMemorySize, 65536);
  hipFuncSetAttribute(reinterpret_cast<const void*>(k_oproj),
                      hipFuncAttributeMaxDynamicSharedMemorySize, 65536);
  hipFuncSetAttribute(reinterpret_cast<const void*>(k_attn),
                      hipFuncAttributeMaxDynamicSharedMemorySize, 131072);

  k_pre<<<896, 256, 0, stream>>>(x, stats, wqkv, wout, w3, wob);
  k_norm<<<1024, 256, 0, stream>>>(x, stats, gamma, beta, xnT);
  k_qkv<<<768, 256, 65536, stream>>>(xnT, w3, bqkv, Qg, Kg, Vg);
  k_attn<<<256, 512, 131072, stream>>>(Qg, Kg, Vg, Op, ml);
  k_oproj<<<256, 256, 65536, stream>>>(wob, Op, ml, bout, x, out);
}